// Round 7
// baseline (21237.537 us; speedup 1.0000x reference)
//
#include <hip/hip_runtime.h>

// NeuralCDE: B=64,T=256,C=16,S=64,H=128. fp32 everywhere (R1: f16 in the
// recursion decorrelates; fp32 passes at the bf16 measurement floor 0.0039).
// History: R4 20.4ms (stream 576KB/stage/CU). R5 62ms (per-stage cross-block
// sync is poison). R6 10.6ms (1024 thr -> 64-VGPR cap -> "resident" W2
// spilled to scratch).
// R7: 64 blocks x 512 threads (8 waves, 256-VGPR budget). ENTIRE model
// CU-resident: W0+W1 in regs (48/thread), W2 cols 0..91 in regs (184/thread,
// rows 2tid & 2tid+1), W2 cols 92..127 in LDS col-major [36][1024] (147.5KB,
// stride-2 access = free 2-way aliasing). Zero per-stage global traffic.
// Readout done in wave-0 registers via shuffles (no per-step barriers).

typedef float float4v __attribute__((ext_vector_type(4)));
typedef float float2v __attribute__((ext_vector_type(2)));

__device__ __forceinline__ float softplusf(float x) {
  return fmaxf(x, 0.f) + log1pf(expf(-fabsf(x)));
}

__device__ __forceinline__ float dot4(float4v a, float4v b) {
  return a.x * b.x + a.y * b.y + a.z * b.z + a.w * b.w;
}

// wave-0 (lanes 0..63) in-register readout + 6D->SO(3) + store for time t.
__device__ __forceinline__ void emit_wave0(int lane, int t, float yv,
                                           const float* __restrict__ row,
                                           const float* __restrict__ rob,
                                           float* __restrict__ outb) {
  float p[6];
#pragma unroll
  for (int o = 0; o < 6; ++o) {
    float s = row[o * 64 + lane] * yv;
    s += __shfl_xor(s, 1);
    s += __shfl_xor(s, 2);
    s += __shfl_xor(s, 4);
    s += __shfl_xor(s, 8);
    s += __shfl_xor(s, 16);
    s += __shfl_xor(s, 32);
    p[o] = s + rob[o];
  }
  if (lane == 0) {
    float a1x = p[0], a1y = p[1], a1z = p[2];
    float a2x = p[3], a2y = p[4], a2z = p[5];
    float n1 = rsqrtf(a1x * a1x + a1y * a1y + a1z * a1z);
    float b1x = a1x * n1, b1y = a1y * n1, b1z = a1z * n1;
    float d = b1x * a2x + b1y * a2y + b1z * a2z;
    float px = a2x - d * b1x, py = a2y - d * b1y, pz = a2z - d * b1z;
    float n2 = rsqrtf(px * px + py * py + pz * pz);
    float b2x = px * n2, b2y = py * n2, b2z = pz * n2;
    float b3x = b1y * b2z - b1z * b2y;
    float b3y = b1z * b2x - b1x * b2z;
    float b3z = b1x * b2y - b1y * b2x;
    float* o = outb + (size_t)t * 9;
    o[0] = b1x; o[1] = b2x; o[2] = b3x;
    o[3] = b1y; o[4] = b2y; o[5] = b3y;
    o[6] = b1z; o[7] = b2z; o[8] = b3z;
  }
}

__global__ __launch_bounds__(512, 2) void cde_main(
    const float* __restrict__ xs,
    const float* __restrict__ icw0, const float* __restrict__ icb0,
    const float* __restrict__ icw1, const float* __restrict__ icb1,
    const float* __restrict__ icw2, const float* __restrict__ icb2,
    const float* __restrict__ vfw0, const float* __restrict__ vfb0,
    const float* __restrict__ vfw1, const float* __restrict__ vfb1,
    const float* __restrict__ vfw2, const float* __restrict__ vfb2,
    const float* __restrict__ row, const float* __restrict__ rob,
    float* __restrict__ out) {
  constexpr float Ac[6][5] = {
      {0.f, 0.f, 0.f, 0.f, 0.f},
      {0.161f, 0.f, 0.f, 0.f, 0.f},
      {-0.008480655492356989f, 0.335480655492357f, 0.f, 0.f, 0.f},
      {2.8971530571054935f, -6.359448489975075f, 4.3622954328695815f, 0.f, 0.f},
      {5.325864828439257f, -11.748883564062828f, 7.4955393428898365f,
       -0.09249506636175525f, 0.f},
      {5.86145544294642f, -12.92096931784711f, 8.159367898576159f,
       -0.071584973281401f, -0.028269050394068383f}};
  constexpr float SCv[6] = {0.f, 0.161f, 0.327f, 0.9f, 0.9800255409045097f, 1.f};
  constexpr float BWv[6] = {0.09646076681806523f, 0.01f, 0.4798896504144996f,
                            1.379008574103742f, -3.290069515436081f,
                            2.324710524099774f};

  const int tid = threadIdx.x;
  const int b = blockIdx.x;  // one block per batch element

  __shared__ float sW2t[36][1024];  // W2 cols 92..127 col-major, 147456 B
  __shared__ __align__(16) float sYt[64];
  __shared__ __align__(16) float sH1[128];
  __shared__ __align__(16) float sH2[128];
  __shared__ float sDx[16];
  __shared__ float sK[6][64];
  __shared__ float sTA[128], sTB[128];

  // ---- one-time: fill LDS W2 tail columns ----
  for (int i = tid; i < 36 * 1024; i += 512) {
    int k = i >> 10, r = i & 1023;
    sW2t[k][r] = vfw2[(size_t)r * 128 + 92 + k];
  }

  // ---- one-time: resident weights in registers ----
  const int r0 = tid * 2, r1 = r0 + 1;            // W2 rows owned
  const float4v* w2p0 = (const float4v*)(vfw2 + (size_t)r0 * 128);
  const float4v* w2p1 = (const float4v*)(vfw2 + (size_t)r1 * 128);
  float4v w2a[23], w2b[23];                        // cols 0..91 of both rows
#pragma unroll
  for (int kk = 0; kk < 23; ++kk) { w2a[kk] = w2p0[kk]; w2b[kk] = w2p1[kk]; }
  const float b2r0 = vfb2[r0], b2r1 = vfb2[r1];
  const int c0 = r0 & 15;                          // dx channel of row r0

  const int ii = tid >> 2, q4 = tid & 3;           // h1/h2: 4 lanes per output
  const float b0i = vfb0[ii], b1i = vfb1[ii];
  const float4v* w0p = (const float4v*)(vfw0 + (size_t)ii * 64 + q4 * 16);
  const float4v* w1p = (const float4v*)(vfw1 + (size_t)ii * 128 + q4 * 32);
  float4v w0r[4], w1r[8];                          // resident W0/W1 slices
#pragma unroll
  for (int kk = 0; kk < 4; ++kk) w0r[kk] = w0p[kk];
#pragma unroll
  for (int kk = 0; kk < 8; ++kk) w1r[kk] = w1p[kk];

  const float* Xb = xs + (size_t)b * 4096;
  float* outb = out + (size_t)b * 2304;

  __syncthreads();

  // ---- initial condition MLP (one-time) ----
  if (tid < 128) {
    float a = icb0[tid];
    const float* wr = icw0 + tid * 16;
#pragma unroll
    for (int k = 0; k < 16; ++k) a += wr[k] * Xb[k];
    sTA[tid] = softplusf(a);
  }
  __syncthreads();
  if (tid < 128) {
    float a = icb1[tid];
    const float* wr = icw1 + tid * 128;
    for (int k = 0; k < 128; ++k) a += wr[k] * sTA[k];
    sTB[tid] = softplusf(a);
  }
  __syncthreads();
  float yreg = 0.f;  // valid on lanes 0..63 (wave 0)
  if (tid < 64) {
    float a = icb2[tid];
    const float* wr = icw2 + tid * 128;
    for (int k = 0; k < 128; ++k) a += wr[k] * sTB[k];
    yreg = a;
    emit_wave0(tid, 0, yreg, row, rob, outb);
  }

  const float hstep = 1.f / 255.f;
  const float invh = 255.f;

#pragma unroll 1
  for (int t = 0; t < 255; ++t) {
    float xi = 0.f, xip1 = 0.f, di = 0.f, dip1 = 0.f;  // lanes 64..79
    if (tid >= 64 && tid < 80) {
      int c = tid - 64;
      xi = Xb[t * 16 + c];
      xip1 = Xb[(t + 1) * 16 + c];
      dip1 = (xip1 - xi) * invh;
      di = (t == 0) ? dip1 : (xi - Xb[(t - 1) * 16 + c]) * invh;
    }
#pragma unroll 1
    for (int j = 0; j < 6; ++j) {
      // ---- phase 0: stage input y_j (wave 0) and dXdt(sc_j) (wave 1) ----
      if (tid < 64) {
        float yt = yreg;
#pragma unroll
        for (int m = 0; m < 5; ++m)
          if (m < j) yt += hstep * Ac[j][m] * sK[m][tid];
        sYt[tid] = yt;
      } else if (tid < 80) {
        float sc = SCv[j];
        float s2 = sc * sc;
        float d1 = (6.f * s2 - 6.f * sc) * invh;
        float d2 = 3.f * s2 - 4.f * sc + 1.f;
        float d4 = 3.f * s2 - 2.f * sc;
        sDx[tid - 64] = d1 * (xi - xip1) + d2 * di + d4 * dip1;
      }
      __syncthreads();
      // ---- h1 = softplus(W0 @ y + b0): W0 resident in regs ----
      {
        const float4v* yv = (const float4v*)(sYt + q4 * 16);
        float s = dot4(w0r[0], yv[0]) + dot4(w0r[1], yv[1]) +
                  dot4(w0r[2], yv[2]) + dot4(w0r[3], yv[3]);
        s += __shfl_xor(s, 1);
        s += __shfl_xor(s, 2);
        if (q4 == 0) sH1[ii] = softplusf(s + b0i);
      }
      __syncthreads();
      // ---- h2 = softplus(W1 @ h1 + b1): W1 resident in regs ----
      {
        const float4v* hv = (const float4v*)sH1 + q4 * 8;
        float s = 0.f;
#pragma unroll
        for (int kk = 0; kk < 8; ++kk) s += dot4(w1r[kk], hv[kk]);
        s += __shfl_xor(s, 1);
        s += __shfl_xor(s, 2);
        if (q4 == 0) sH2[ii] = softplusf(s + b1i);
      }
      __syncthreads();
      // ---- k: rows 2tid,2tid+1 of A = tanh(W2 h2 + b2), * dx, reduce ----
      {
        const float4v* hv = (const float4v*)sH2;
        float s0 = 0.f, s1 = 0.f;
#pragma unroll
        for (int kk = 0; kk < 23; ++kk) {
          float4v h = hv[kk];
          s0 += dot4(w2a[kk], h);
          s1 += dot4(w2b[kk], h);
        }
#pragma unroll
        for (int k = 0; k < 36; ++k) {
          float2v w = *(const float2v*)&sW2t[k][r0];  // ds_read_b64
          float hk = sH2[92 + k];                      // broadcast
          s0 += w.x * hk;
          s1 += w.y * hk;
        }
        float f = tanhf(s0 + b2r0) * sDx[c0] + tanhf(s1 + b2r1) * sDx[c0 + 1];
        f += __shfl_xor(f, 1);
        f += __shfl_xor(f, 2);
        f += __shfl_xor(f, 4);
        if ((tid & 7) == 0) sK[j][tid >> 3] = f;
      }
      __syncthreads();
    }
    // ---- y_{t+1} = y_t + h * sum BW_m k_m; emit (wave 0, in-register) ----
    if (tid < 64) {
      float yn = yreg;
#pragma unroll
      for (int m = 0; m < 6; ++m) yn += hstep * BWv[m] * sK[m][tid];
      yreg = yn;
      emit_wave0(tid, t + 1, yreg, row, rob, outb);
    }
    // no barrier needed: next phase-0 write of sYt/sDx is followed by a
    // barrier before any cross-wave read, and sK is rewritten only after
    // three more barriers.
  }
}

extern "C" void kernel_launch(void* const* d_in, const int* in_sizes, int n_in,
                              void* d_out, int out_size, void* d_ws,
                              size_t ws_size, hipStream_t stream) {
  (void)in_sizes; (void)n_in; (void)out_size; (void)d_ws; (void)ws_size;
  const float* xs   = (const float*)d_in[0];
  const float* icw0 = (const float*)d_in[1];
  const float* icb0 = (const float*)d_in[2];
  const float* icw1 = (const float*)d_in[3];
  const float* icb1 = (const float*)d_in[4];
  const float* icw2 = (const float*)d_in[5];
  const float* icb2 = (const float*)d_in[6];
  const float* vfw0 = (const float*)d_in[7];
  const float* vfb0 = (const float*)d_in[8];
  const float* vfw1 = (const float*)d_in[9];
  const float* vfb1 = (const float*)d_in[10];
  const float* vfw2 = (const float*)d_in[11];
  const float* vfb2 = (const float*)d_in[12];
  const float* row  = (const float*)d_in[13];
  const float* rob  = (const float*)d_in[14];

  hipLaunchKernelGGL(cde_main, dim3(64), dim3(512), 0, stream,
                     xs, icw0, icb0, icw1, icb1, icw2, icb2,
                     vfw0, vfb0, vfw1, vfb1, vfw2, vfb2, row, rob,
                     (float*)d_out);
}

// Round 8
// 9086.955 us; speedup vs baseline: 2.3371x; 2.3371x over previous
//
#include <hip/hip_runtime.h>

// NeuralCDE: B=64,T=256,C=16,S=64,H=128. fp32 everywhere (f16/bf16 anywhere
// in the 255-step recursion decorrelates; fp32 sits at the bf16 floor .0039).
// History: R4 20.4ms (L2 re-stream 576KB/stage/CU). R5 62ms (per-stage
// cross-block sync = L2 coherence poison). R6 10.6ms (64-VGPR cap, spill).
// R7 21.2ms (launch_bounds(512,2) -> 128-VGPR cap -> 232 resident regs
// spilled; WRITE_SIZE 138MB of scratch traffic).
// MEASURED LESSON: 2nd launch_bounds arg acts as min-BLOCKS-per-CU here:
// (512,2)->128 regs, (1024)->64. So (512,1) -> 8 waves/CU -> 2 waves/SIMD
// -> 256-VGPR budget.
// R8: 64 blocks x 512 threads, launch_bounds(512,1). Model fully CU-resident:
//   regs: W2 rows 2tid,2tid+1 cols 0..89 (180), W0 slice (16), W1 slice (32)
//   LDS:  W2 cols 90..127 col-major [38][1024] (155.6KB) + 2.9KB activations
// Zero per-stage global traffic. Readout in wave-0 registers.

typedef float float4v __attribute__((ext_vector_type(4)));
typedef float float2v __attribute__((ext_vector_type(2)));

__device__ __forceinline__ float softplusf(float x) {
  return fmaxf(x, 0.f) + log1pf(expf(-fabsf(x)));
}

__device__ __forceinline__ float dot4(float4v a, float4v b) {
  return a.x * b.x + a.y * b.y + a.z * b.z + a.w * b.w;
}

// wave-0 (lanes 0..63) in-register readout + 6D->SO(3) + store for time t.
__device__ __forceinline__ void emit_wave0(int lane, int t, float yv,
                                           const float* __restrict__ row,
                                           const float* __restrict__ rob,
                                           float* __restrict__ outb) {
  float p[6];
#pragma unroll
  for (int o = 0; o < 6; ++o) {
    float s = row[o * 64 + lane] * yv;
    s += __shfl_xor(s, 1);
    s += __shfl_xor(s, 2);
    s += __shfl_xor(s, 4);
    s += __shfl_xor(s, 8);
    s += __shfl_xor(s, 16);
    s += __shfl_xor(s, 32);
    p[o] = s + rob[o];
  }
  if (lane == 0) {
    float a1x = p[0], a1y = p[1], a1z = p[2];
    float a2x = p[3], a2y = p[4], a2z = p[5];
    float n1 = rsqrtf(a1x * a1x + a1y * a1y + a1z * a1z);
    float b1x = a1x * n1, b1y = a1y * n1, b1z = a1z * n1;
    float d = b1x * a2x + b1y * a2y + b1z * a2z;
    float px = a2x - d * b1x, py = a2y - d * b1y, pz = a2z - d * b1z;
    float n2 = rsqrtf(px * px + py * py + pz * pz);
    float b2x = px * n2, b2y = py * n2, b2z = pz * n2;
    float b3x = b1y * b2z - b1z * b2y;
    float b3y = b1z * b2x - b1x * b2z;
    float b3z = b1x * b2y - b1y * b2x;
    float* o = outb + (size_t)t * 9;
    o[0] = b1x; o[1] = b2x; o[2] = b3x;
    o[3] = b1y; o[4] = b2y; o[5] = b3y;
    o[6] = b1z; o[7] = b2z; o[8] = b3z;
  }
}

__global__ __launch_bounds__(512, 1) void cde_main(
    const float* __restrict__ xs,
    const float* __restrict__ icw0, const float* __restrict__ icb0,
    const float* __restrict__ icw1, const float* __restrict__ icb1,
    const float* __restrict__ icw2, const float* __restrict__ icb2,
    const float* __restrict__ vfw0, const float* __restrict__ vfb0,
    const float* __restrict__ vfw1, const float* __restrict__ vfb1,
    const float* __restrict__ vfw2, const float* __restrict__ vfb2,
    const float* __restrict__ row, const float* __restrict__ rob,
    float* __restrict__ out) {
  constexpr float Ac[6][5] = {
      {0.f, 0.f, 0.f, 0.f, 0.f},
      {0.161f, 0.f, 0.f, 0.f, 0.f},
      {-0.008480655492356989f, 0.335480655492357f, 0.f, 0.f, 0.f},
      {2.8971530571054935f, -6.359448489975075f, 4.3622954328695815f, 0.f, 0.f},
      {5.325864828439257f, -11.748883564062828f, 7.4955393428898365f,
       -0.09249506636175525f, 0.f},
      {5.86145544294642f, -12.92096931784711f, 8.159367898576159f,
       -0.071584973281401f, -0.028269050394068383f}};
  constexpr float SCv[6] = {0.f, 0.161f, 0.327f, 0.9f, 0.9800255409045097f, 1.f};
  constexpr float BWv[6] = {0.09646076681806523f, 0.01f, 0.4798896504144996f,
                            1.379008574103742f, -3.290069515436081f,
                            2.324710524099774f};

  const int tid = threadIdx.x;
  const int b = blockIdx.x;  // one block per batch element

  __shared__ float sW2t[38][1024];         // W2 cols 90..127 col-major
  __shared__ __align__(16) float sYt[64];
  __shared__ __align__(16) float sH1[128];
  __shared__ __align__(16) float sH2[128];
  __shared__ float sDx[16];
  __shared__ float sK[6][64];

  // ---- one-time: fill LDS W2 tail columns ----
  for (int i = tid; i < 38 * 1024; i += 512) {
    int k = i >> 10, r = i & 1023;
    sW2t[k][r] = vfw2[(size_t)r * 128 + 90 + k];
  }

  // ---- one-time: resident weights in registers ----
  const int r0 = tid * 2, r1 = r0 + 1;  // W2 rows owned
  const float4v* w2p0 = (const float4v*)(vfw2 + (size_t)r0 * 128);
  const float4v* w2p1 = (const float4v*)(vfw2 + (size_t)r1 * 128);
  float4v w2a[22], w2b[22];              // cols 0..87
#pragma unroll
  for (int kk = 0; kk < 22; ++kk) { w2a[kk] = w2p0[kk]; w2b[kk] = w2p1[kk]; }
  float2v w2a2 = *(const float2v*)(vfw2 + (size_t)r0 * 128 + 88);  // cols 88,89
  float2v w2b2 = *(const float2v*)(vfw2 + (size_t)r1 * 128 + 88);
  const float b2r0 = vfb2[r0], b2r1 = vfb2[r1];
  const int c0 = r0 & 15;                // dx channel of row r0

  const int ii = tid >> 2, q4 = tid & 3; // h1/h2: 4 lanes per output
  const float b0i = vfb0[ii], b1i = vfb1[ii];
  const float4v* w0p = (const float4v*)(vfw0 + (size_t)ii * 64 + q4 * 16);
  const float4v* w1p = (const float4v*)(vfw1 + (size_t)ii * 128 + q4 * 32);
  float4v w0r[4], w1r[8];                // resident W0/W1 slices
#pragma unroll
  for (int kk = 0; kk < 4; ++kk) w0r[kk] = w0p[kk];
#pragma unroll
  for (int kk = 0; kk < 8; ++kk) w1r[kk] = w1p[kk];

  const float* Xb = xs + (size_t)b * 4096;
  float* outb = out + (size_t)b * 2304;

  __syncthreads();

  // ---- initial condition MLP (one-time; sTA := sK[0..], sTB := sH1) ----
  float* sTA = &sK[0][0];
  float* sTB = sH1;
  if (tid < 128) {
    float a = icb0[tid];
    const float* wr = icw0 + tid * 16;
#pragma unroll
    for (int k = 0; k < 16; ++k) a += wr[k] * Xb[k];
    sTA[tid] = softplusf(a);
  }
  __syncthreads();
  if (tid < 128) {
    float a = icb1[tid];
    const float* wr = icw1 + tid * 128;
    for (int k = 0; k < 128; ++k) a += wr[k] * sTA[k];
    sTB[tid] = softplusf(a);
  }
  __syncthreads();
  float yreg = 0.f;  // valid on lanes 0..63 (wave 0)
  if (tid < 64) {
    float a = icb2[tid];
    const float* wr = icw2 + tid * 128;
    for (int k = 0; k < 128; ++k) a += wr[k] * sTB[k];
    yreg = a;
    emit_wave0(tid, 0, yreg, row, rob, outb);
  }
  __syncthreads();  // sTA/sTB aliases done before sK/sH1 reused

  const float hstep = 1.f / 255.f;
  const float invh = 255.f;

#pragma unroll 1
  for (int t = 0; t < 255; ++t) {
    float xi = 0.f, xip1 = 0.f, di = 0.f, dip1 = 0.f;  // lanes 64..79
    if (tid >= 64 && tid < 80) {
      int c = tid - 64;
      xi = Xb[t * 16 + c];
      xip1 = Xb[(t + 1) * 16 + c];
      dip1 = (xip1 - xi) * invh;
      di = (t == 0) ? dip1 : (xi - Xb[(t - 1) * 16 + c]) * invh;
    }
#pragma unroll 1
    for (int j = 0; j < 6; ++j) {
      // ---- phase 0: stage input y_j (wave 0) and dXdt(sc_j) (wave 1) ----
      if (tid < 64) {
        float yt = yreg;
#pragma unroll
        for (int m = 0; m < 5; ++m)
          if (m < j) yt += hstep * Ac[j][m] * sK[m][tid];
        sYt[tid] = yt;
      } else if (tid < 80) {
        float sc = SCv[j];
        float s2 = sc * sc;
        float d1 = (6.f * s2 - 6.f * sc) * invh;
        float d2 = 3.f * s2 - 4.f * sc + 1.f;
        float d4 = 3.f * s2 - 2.f * sc;
        sDx[tid - 64] = d1 * (xi - xip1) + d2 * di + d4 * dip1;
      }
      __syncthreads();
      // ---- h1 = softplus(W0 @ y + b0): W0 resident ----
      {
        const float4v* yv = (const float4v*)(sYt + q4 * 16);
        float s = dot4(w0r[0], yv[0]) + dot4(w0r[1], yv[1]) +
                  dot4(w0r[2], yv[2]) + dot4(w0r[3], yv[3]);
        s += __shfl_xor(s, 1);
        s += __shfl_xor(s, 2);
        if (q4 == 0) sH1[ii] = softplusf(s + b0i);
      }
      __syncthreads();
      // ---- h2 = softplus(W1 @ h1 + b1): W1 resident ----
      {
        const float4v* hv = (const float4v*)sH1 + q4 * 8;
        float s = 0.f;
#pragma unroll
        for (int kk = 0; kk < 8; ++kk) s += dot4(w1r[kk], hv[kk]);
        s += __shfl_xor(s, 1);
        s += __shfl_xor(s, 2);
        if (q4 == 0) sH2[ii] = softplusf(s + b1i);
      }
      __syncthreads();
      // ---- k: rows 2tid,2tid+1 of A = tanh(W2 h2 + b2), * dx, reduce ----
      {
        const float4v* hv = (const float4v*)sH2;
        float s0 = 0.f, s1 = 0.f;
#pragma unroll
        for (int kk = 0; kk < 22; ++kk) {
          float4v h = hv[kk];
          s0 += dot4(w2a[kk], h);
          s1 += dot4(w2b[kk], h);
        }
        {
          float2v h88 = *(const float2v*)(sH2 + 88);
          s0 += w2a2.x * h88.x + w2a2.y * h88.y;
          s1 += w2b2.x * h88.x + w2b2.y * h88.y;
        }
#pragma unroll 1
        for (int k = 0; k < 38; ++k) {
          float2v w = *(const float2v*)&sW2t[k][r0];  // ds_read_b64, 2-way ok
          float hk = sH2[90 + k];                      // broadcast
          s0 += w.x * hk;
          s1 += w.y * hk;
        }
        float f = tanhf(s0 + b2r0) * sDx[c0] + tanhf(s1 + b2r1) * sDx[c0 + 1];
        f += __shfl_xor(f, 1);
        f += __shfl_xor(f, 2);
        f += __shfl_xor(f, 4);
        if ((tid & 7) == 0) sK[j][tid >> 3] = f;
      }
      __syncthreads();
    }
    // ---- y_{t+1} = y_t + h * sum BW_m k_m; emit (wave 0, in-register) ----
    if (tid < 64) {
      float yn = yreg;
#pragma unroll
      for (int m = 0; m < 6; ++m) yn += hstep * BWv[m] * sK[m][tid];
      yreg = yn;
      emit_wave0(tid, t + 1, yreg, row, rob, outb);
    }
    // no trailing barrier needed: sYt/sDx rewrites are barrier-protected at
    // the top of the next stage; sK[0] is rewritten only after 3 barriers.
  }
}

extern "C" void kernel_launch(void* const* d_in, const int* in_sizes, int n_in,
                              void* d_out, int out_size, void* d_ws,
                              size_t ws_size, hipStream_t stream) {
  (void)in_sizes; (void)n_in; (void)out_size; (void)d_ws; (void)ws_size;
  const float* xs   = (const float*)d_in[0];
  const float* icw0 = (const float*)d_in[1];
  const float* icb0 = (const float*)d_in[2];
  const float* icw1 = (const float*)d_in[3];
  const float* icb1 = (const float*)d_in[4];
  const float* icw2 = (const float*)d_in[5];
  const float* icb2 = (const float*)d_in[6];
  const float* vfw0 = (const float*)d_in[7];
  const float* vfb0 = (const float*)d_in[8];
  const float* vfw1 = (const float*)d_in[9];
  const float* vfb1 = (const float*)d_in[10];
  const float* vfw2 = (const float*)d_in[11];
  const float* vfb2 = (const float*)d_in[12];
  const float* row  = (const float*)d_in[13];
  const float* rob  = (const float*)d_in[14];

  hipLaunchKernelGGL(cde_main, dim3(64), dim3(512), 0, stream,
                     xs, icw0, icb0, icw1, icb1, icw2, icb2,
                     vfw0, vfb0, vfw1, vfb1, vfw2, vfb2, row, rob,
                     (float*)d_out);
}

// Round 9
// 8668.159 us; speedup vs baseline: 2.4501x; 1.0483x over previous
//
#include <hip/hip_runtime.h>

// NeuralCDE: B=64,T=256,C=16,S=64,H=128. fp32 everywhere (f16/bf16 anywhere
// in the 255-step recursion decorrelates; fp32 sits at the bf16 floor .0039).
// History: R4 20.4ms (stream 576KB/stage/CU). R5 62ms (per-stage cross-block
// sync poison). R6 10.6ms (64-VGPR cap spill). R7 21.2ms ((512,2)->128-reg
// cap -> spill, WRITE 138MB). R8 9.1ms ((512,1): no spill BUT VGPR=128 —
// compiler REMATERIALIZED the loop-invariant weight loads instead of keeping
// them resident; 44-deep L2 load chain re-walked every stage).
// R9: make residency un-defeatable: after one-time load, pass every resident
// reg through asm volatile("" : "+v"(x)) — opaque SSA value, remat illegal.
// Pinned: W2 rows 2tid,2tid+1 cols 0..83 (168 regs) + W0 slice (16) + W1
// slice (32) = 216. Streamed/stage: W2 cols 84..89 (12 regs, overlapped).
// LDS: W2 cols 90..127 col-major [38][1024] + activations. Budget ~250/256.

typedef float float4v __attribute__((ext_vector_type(4)));
typedef float float2v __attribute__((ext_vector_type(2)));

__device__ __forceinline__ float softplusf(float x) {
  return fmaxf(x, 0.f) + log1pf(expf(-fabsf(x)));
}

__device__ __forceinline__ float dot4(float4v a, float4v b) {
  return a.x * b.x + a.y * b.y + a.z * b.z + a.w * b.w;
}

// wave-0 (lanes 0..63) in-register readout + 6D->SO(3) + store for time t.
__device__ __forceinline__ void emit_wave0(int lane, int t, float yv,
                                           const float* __restrict__ row,
                                           const float* __restrict__ rob,
                                           float* __restrict__ outb) {
  float p[6];
#pragma unroll
  for (int o = 0; o < 6; ++o) {
    float s = row[o * 64 + lane] * yv;
    s += __shfl_xor(s, 1);
    s += __shfl_xor(s, 2);
    s += __shfl_xor(s, 4);
    s += __shfl_xor(s, 8);
    s += __shfl_xor(s, 16);
    s += __shfl_xor(s, 32);
    p[o] = s + rob[o];
  }
  if (lane == 0) {
    float a1x = p[0], a1y = p[1], a1z = p[2];
    float a2x = p[3], a2y = p[4], a2z = p[5];
    float n1 = rsqrtf(a1x * a1x + a1y * a1y + a1z * a1z);
    float b1x = a1x * n1, b1y = a1y * n1, b1z = a1z * n1;
    float d = b1x * a2x + b1y * a2y + b1z * a2z;
    float px = a2x - d * b1x, py = a2y - d * b1y, pz = a2z - d * b1z;
    float n2 = rsqrtf(px * px + py * py + pz * pz);
    float b2x = px * n2, b2y = py * n2, b2z = pz * n2;
    float b3x = b1y * b2z - b1z * b2y;
    float b3y = b1z * b2x - b1x * b2z;
    float b3z = b1x * b2y - b1y * b2x;
    float* o = outb + (size_t)t * 9;
    o[0] = b1x; o[1] = b2x; o[2] = b3x;
    o[3] = b1y; o[4] = b2y; o[5] = b3y;
    o[6] = b1z; o[7] = b2z; o[8] = b3z;
  }
}

__global__ __launch_bounds__(512, 1) void cde_main(
    const float* __restrict__ xs,
    const float* __restrict__ icw0, const float* __restrict__ icb0,
    const float* __restrict__ icw1, const float* __restrict__ icb1,
    const float* __restrict__ icw2, const float* __restrict__ icb2,
    const float* __restrict__ vfw0, const float* __restrict__ vfb0,
    const float* __restrict__ vfw1, const float* __restrict__ vfb1,
    const float* __restrict__ vfw2, const float* __restrict__ vfb2,
    const float* __restrict__ row, const float* __restrict__ rob,
    float* __restrict__ out) {
  constexpr float Ac[6][5] = {
      {0.f, 0.f, 0.f, 0.f, 0.f},
      {0.161f, 0.f, 0.f, 0.f, 0.f},
      {-0.008480655492356989f, 0.335480655492357f, 0.f, 0.f, 0.f},
      {2.8971530571054935f, -6.359448489975075f, 4.3622954328695815f, 0.f, 0.f},
      {5.325864828439257f, -11.748883564062828f, 7.4955393428898365f,
       -0.09249506636175525f, 0.f},
      {5.86145544294642f, -12.92096931784711f, 8.159367898576159f,
       -0.071584973281401f, -0.028269050394068383f}};
  constexpr float SCv[6] = {0.f, 0.161f, 0.327f, 0.9f, 0.9800255409045097f, 1.f};
  constexpr float BWv[6] = {0.09646076681806523f, 0.01f, 0.4798896504144996f,
                            1.379008574103742f, -3.290069515436081f,
                            2.324710524099774f};

  const int tid = threadIdx.x;
  const int b = blockIdx.x;  // one block per batch element

  __shared__ float sW2t[38][1024];         // W2 cols 90..127 col-major
  __shared__ __align__(16) float sYt[64];
  __shared__ __align__(16) float sH1[128];
  __shared__ __align__(16) float sH2[128];
  __shared__ float sDx[16];
  __shared__ float sK[6][64];

  // ---- one-time: fill LDS W2 tail columns ----
  for (int i = tid; i < 38 * 1024; i += 512) {
    int k = i >> 10, r = i & 1023;
    sW2t[k][r] = vfw2[(size_t)r * 128 + 90 + k];
  }

  // ---- one-time: resident weights in registers, PINNED via asm opacity ----
  const int r0 = tid * 2, r1 = r0 + 1;  // W2 rows owned
  const float4v* w2p0 = (const float4v*)(vfw2 + (size_t)r0 * 128);
  const float4v* w2p1 = (const float4v*)(vfw2 + (size_t)r1 * 128);
  float4v w2a[21], w2b[21];              // cols 0..83 of both rows
#pragma unroll
  for (int kk = 0; kk < 21; ++kk) { w2a[kk] = w2p0[kk]; w2b[kk] = w2p1[kk]; }
#pragma unroll
  for (int kk = 0; kk < 21; ++kk) {
    asm volatile("" : "+v"(w2a[kk]));
    asm volatile("" : "+v"(w2b[kk]));
  }
  const float b2r0 = vfb2[r0], b2r1 = vfb2[r1];
  const int c0 = r0 & 15;                // dx channel of row r0

  const int ii = tid >> 2, q4 = tid & 3; // h1/h2: 4 lanes per output
  const float b0i = vfb0[ii], b1i = vfb1[ii];
  const float4v* w0p = (const float4v*)(vfw0 + (size_t)ii * 64 + q4 * 16);
  const float4v* w1p = (const float4v*)(vfw1 + (size_t)ii * 128 + q4 * 32);
  float4v w0r[4], w1r[8];                // resident W0/W1 slices
#pragma unroll
  for (int kk = 0; kk < 4; ++kk) w0r[kk] = w0p[kk];
#pragma unroll
  for (int kk = 0; kk < 8; ++kk) w1r[kk] = w1p[kk];
#pragma unroll
  for (int kk = 0; kk < 4; ++kk) asm volatile("" : "+v"(w0r[kk]));
#pragma unroll
  for (int kk = 0; kk < 8; ++kk) asm volatile("" : "+v"(w1r[kk]));

  const float* Xb = xs + (size_t)b * 4096;
  float* outb = out + (size_t)b * 2304;

  __syncthreads();

  // ---- initial condition MLP (one-time; sTA := sK[0..], sTB := sH1) ----
  float* sTA = &sK[0][0];
  float* sTB = sH1;
  if (tid < 128) {
    float a = icb0[tid];
    const float* wr = icw0 + tid * 16;
#pragma unroll
    for (int k = 0; k < 16; ++k) a += wr[k] * Xb[k];
    sTA[tid] = softplusf(a);
  }
  __syncthreads();
  if (tid < 128) {
    float a = icb1[tid];
    const float* wr = icw1 + tid * 128;
    for (int k = 0; k < 128; ++k) a += wr[k] * sTA[k];
    sTB[tid] = softplusf(a);
  }
  __syncthreads();
  float yreg = 0.f;  // valid on lanes 0..63 (wave 0)
  if (tid < 64) {
    float a = icb2[tid];
    const float* wr = icw2 + tid * 128;
    for (int k = 0; k < 128; ++k) a += wr[k] * sTB[k];
    yreg = a;
    emit_wave0(tid, 0, yreg, row, rob, outb);
  }
  __syncthreads();  // sTA/sTB aliases done before sK/sH1 reused

  const float hstep = 1.f / 255.f;
  const float invh = 255.f;

#pragma unroll 1
  for (int t = 0; t < 255; ++t) {
    float xi = 0.f, xip1 = 0.f, di = 0.f, dip1 = 0.f;  // lanes 64..79
    if (tid >= 64 && tid < 80) {
      int c = tid - 64;
      xi = Xb[t * 16 + c];
      xip1 = Xb[(t + 1) * 16 + c];
      dip1 = (xip1 - xi) * invh;
      di = (t == 0) ? dip1 : (xi - Xb[(t - 1) * 16 + c]) * invh;
    }
#pragma unroll 1
    for (int j = 0; j < 6; ++j) {
      // ---- streamed W2 tail cols 84..89 (issued early, used at k-phase) --
      float4v w2sa = w2p0[21], w2sb = w2p1[21];                   // 84..87
      float2v w2ta = *(const float2v*)(vfw2 + (size_t)r0 * 128 + 88);
      float2v w2tb = *(const float2v*)(vfw2 + (size_t)r1 * 128 + 88);
      // ---- phase 0: stage input y_j (wave 0) and dXdt(sc_j) (wave 1) ----
      if (tid < 64) {
        float yt = yreg;
#pragma unroll
        for (int m = 0; m < 5; ++m)
          if (m < j) yt += hstep * Ac[j][m] * sK[m][tid];
        sYt[tid] = yt;
      } else if (tid < 80) {
        float sc = SCv[j];
        float s2 = sc * sc;
        float d1 = (6.f * s2 - 6.f * sc) * invh;
        float d2 = 3.f * s2 - 4.f * sc + 1.f;
        float d4 = 3.f * s2 - 2.f * sc;
        sDx[tid - 64] = d1 * (xi - xip1) + d2 * di + d4 * dip1;
      }
      __syncthreads();
      // ---- h1 = softplus(W0 @ y + b0): W0 pinned ----
      {
        const float4v* yv = (const float4v*)(sYt + q4 * 16);
        float s = dot4(w0r[0], yv[0]) + dot4(w0r[1], yv[1]) +
                  dot4(w0r[2], yv[2]) + dot4(w0r[3], yv[3]);
        s += __shfl_xor(s, 1);
        s += __shfl_xor(s, 2);
        if (q4 == 0) sH1[ii] = softplusf(s + b0i);
      }
      __syncthreads();
      // ---- h2 = softplus(W1 @ h1 + b1): W1 pinned ----
      {
        const float4v* hv = (const float4v*)sH1 + q4 * 8;
        float s = 0.f;
#pragma unroll
        for (int kk = 0; kk < 8; ++kk) s += dot4(w1r[kk], hv[kk]);
        s += __shfl_xor(s, 1);
        s += __shfl_xor(s, 2);
        if (q4 == 0) sH2[ii] = softplusf(s + b1i);
      }
      __syncthreads();
      // ---- k: rows 2tid,2tid+1 of A = tanh(W2 h2 + b2), * dx, reduce ----
      {
        const float4v* hv = (const float4v*)sH2;
        float s0 = 0.f, s1 = 0.f;
#pragma unroll
        for (int kk = 0; kk < 21; ++kk) {
          float4v h = hv[kk];
          s0 += dot4(w2a[kk], h);
          s1 += dot4(w2b[kk], h);
        }
        {
          float4v h84 = hv[21];
          s0 += dot4(w2sa, h84);
          s1 += dot4(w2sb, h84);
          float2v h88 = *(const float2v*)(sH2 + 88);
          s0 += w2ta.x * h88.x + w2ta.y * h88.y;
          s1 += w2tb.x * h88.x + w2tb.y * h88.y;
        }
#pragma unroll 4
        for (int k = 0; k < 38; ++k) {
          float2v w = *(const float2v*)&sW2t[k][r0];  // stride-2: free 2-way
          float hk = sH2[90 + k];                     // broadcast
          s0 += w.x * hk;
          s1 += w.y * hk;
        }
        float f = tanhf(s0 + b2r0) * sDx[c0] + tanhf(s1 + b2r1) * sDx[c0 + 1];
        f += __shfl_xor(f, 1);
        f += __shfl_xor(f, 2);
        f += __shfl_xor(f, 4);
        if ((tid & 7) == 0) sK[j][tid >> 3] = f;
      }
      __syncthreads();
    }
    // ---- y_{t+1} = y_t + h * sum BW_m k_m; emit (wave 0, in-register) ----
    if (tid < 64) {
      float yn = yreg;
#pragma unroll
      for (int m = 0; m < 6; ++m) yn += hstep * BWv[m] * sK[m][tid];
      yreg = yn;
      emit_wave0(tid, t + 1, yreg, row, rob, outb);
    }
    // no trailing barrier needed: sYt/sDx rewrites are barrier-protected at
    // the top of the next stage; sK[0] is rewritten only after 3 barriers.
  }
}

extern "C" void kernel_launch(void* const* d_in, const int* in_sizes, int n_in,
                              void* d_out, int out_size, void* d_ws,
                              size_t ws_size, hipStream_t stream) {
  (void)in_sizes; (void)n_in; (void)out_size; (void)d_ws; (void)ws_size;
  const float* xs   = (const float*)d_in[0];
  const float* icw0 = (const float*)d_in[1];
  const float* icb0 = (const float*)d_in[2];
  const float* icw1 = (const float*)d_in[3];
  const float* icb1 = (const float*)d_in[4];
  const float* icw2 = (const float*)d_in[5];
  const float* icb2 = (const float*)d_in[6];
  const float* vfw0 = (const float*)d_in[7];
  const float* vfb0 = (const float*)d_in[8];
  const float* vfw1 = (const float*)d_in[9];
  const float* vfb1 = (const float*)d_in[10];
  const float* vfw2 = (const float*)d_in[11];
  const float* vfb2 = (const float*)d_in[12];
  const float* row  = (const float*)d_in[13];
  const float* rob  = (const float*)d_in[14];

  hipLaunchKernelGGL(cde_main, dim3(64), dim3(512), 0, stream,
                     xs, icw0, icb0, icw1, icb1, icw2, icb2,
                     vfw0, vfb0, vfw1, vfb1, vfw2, vfb2, row, rob,
                     (float*)d_out);
}